// Round 1
// baseline (307.532 us; speedup 1.0000x reference)
//
#include <hip/hip_runtime.h>

#define ROWCAP 1024   // LDS capacity for rows-per-group (actual max ~25 for 8192 draws over 1024 groups)

__device__ __forceinline__ float4 exp4(float4 v) {
    float4 r;
    r.x = __expf(v.x); r.y = __expf(v.y); r.z = __expf(v.z); r.w = __expf(v.w);
    return r;
}

__device__ __forceinline__ float wave_reduce(float v) {
    #pragma unroll
    for (int off = 32; off > 0; off >>= 1) v += __shfl_down(v, off, 64);
    return v;
}

// ---------------- Kernel A (path1): segment sums of exp(theta0) + loss_a, store s0 ----------------
// grid = 1024 (one block per group), block = 256
__global__ __launch_bounds__(256) void kA(const float4* __restrict__ theta0,
                                          const float4* __restrict__ obs0,
                                          const int* __restrict__ idx,
                                          float4* __restrict__ s0,
                                          float* __restrict__ lossA) {
    __shared__ int rows[ROWCAP];
    __shared__ int cnt;
    __shared__ float wsum[4];
    const int g = blockIdx.x;
    const int tid = threadIdx.x;
    if (tid == 0) cnt = 0;
    __syncthreads();
    for (int i = tid; i < 8192; i += 256) {
        if (idx[i] == g) {
            int p = atomicAdd(&cnt, 1);
            if (p < ROWCAP) rows[p] = i;
        }
    }
    __syncthreads();
    const int n = min(cnt, ROWCAP);

    float4 s0acc = {0.f,0.f,0.f,0.f}, s1acc = {0.f,0.f,0.f,0.f};
    float4 s2acc = {0.f,0.f,0.f,0.f}, s3acc = {0.f,0.f,0.f,0.f};
    for (int r = 0; r < n; ++r) {
        const float4* rowp = theta0 + (size_t)rows[r] * 1024;
        float4 v0 = rowp[tid];
        float4 v1 = rowp[tid + 256];
        float4 v2 = rowp[tid + 512];
        float4 v3 = rowp[tid + 768];
        float4 e;
        e = exp4(v0); s0acc.x += e.x; s0acc.y += e.y; s0acc.z += e.z; s0acc.w += e.w;
        e = exp4(v1); s1acc.x += e.x; s1acc.y += e.y; s1acc.z += e.z; s1acc.w += e.w;
        e = exp4(v2); s2acc.x += e.x; s2acc.y += e.y; s2acc.z += e.z; s2acc.w += e.w;
        e = exp4(v3); s3acc.x += e.x; s3acc.y += e.y; s3acc.z += e.z; s3acc.w += e.w;
    }

    float lacc = 0.f;
    const size_t base = (size_t)g * 1024;
    float4 sv[4] = {s0acc, s1acc, s2acc, s3acc};
    #pragma unroll
    for (int j = 0; j < 4; ++j) {
        size_t o = base + tid + j * 256;
        s0[o] = sv[j];
        float4 ob = obs0[o];
        float dx = ob.x - sv[j].x, dy = ob.y - sv[j].y;
        float dz = ob.z - sv[j].z, dw = ob.w - sv[j].w;
        lacc += dx*dx + dy*dy + dz*dz + dw*dw;
    }

    lacc = wave_reduce(lacc);
    if ((tid & 63) == 0) wsum[tid >> 6] = lacc;
    __syncthreads();
    if (tid == 0) atomicAdd(lossA, wsum[0] + wsum[1] + wsum[2] + wsum[3]);
}

// ---------------- Kernel A2 (path2 fallback): atomicAdd into replicated p2 ----------------
__global__ __launch_bounds__(256) void kA2(const float4* __restrict__ theta0,
                                           const float4* __restrict__ obs0,
                                           const int* __restrict__ idx,
                                           float* __restrict__ p2r,
                                           float* __restrict__ lossA,
                                           int R) {
    __shared__ int rows[ROWCAP];
    __shared__ int cnt;
    __shared__ float wsum[4];
    const int g = blockIdx.x;
    const int tid = threadIdx.x;
    if (tid == 0) cnt = 0;
    __syncthreads();
    for (int i = tid; i < 8192; i += 256) {
        if (idx[i] == g) {
            int p = atomicAdd(&cnt, 1);
            if (p < ROWCAP) rows[p] = i;
        }
    }
    __syncthreads();
    const int n = min(cnt, ROWCAP);

    float4 sv[4];
    #pragma unroll
    for (int j = 0; j < 4; ++j) sv[j] = make_float4(0.f,0.f,0.f,0.f);
    for (int r = 0; r < n; ++r) {
        const float4* rowp = theta0 + (size_t)rows[r] * 1024;
        #pragma unroll
        for (int j = 0; j < 4; ++j) {
            float4 e = exp4(rowp[tid + j * 256]);
            sv[j].x += e.x; sv[j].y += e.y; sv[j].z += e.z; sv[j].w += e.w;
        }
    }
    float* dst = p2r + (size_t)(g % R) * 4096;
    float lacc = 0.f;
    #pragma unroll
    for (int j = 0; j < 4; ++j) {
        int c4 = tid + j * 256;
        atomicAdd(&dst[4*c4+0], sv[j].x);
        atomicAdd(&dst[4*c4+1], sv[j].y);
        atomicAdd(&dst[4*c4+2], sv[j].z);
        atomicAdd(&dst[4*c4+3], sv[j].w);
        float4 ob = obs0[(size_t)g * 1024 + c4];
        float dx = ob.x - sv[j].x, dy = ob.y - sv[j].y;
        float dz = ob.z - sv[j].z, dw = ob.w - sv[j].w;
        lacc += dx*dx + dy*dy + dz*dz + dw*dw;
    }
    lacc = wave_reduce(lacc);
    if ((tid & 63) == 0) wsum[tid >> 6] = lacc;
    __syncthreads();
    if (tid == 0) atomicAdd(lossA, wsum[0] + wsum[1] + wsum[2] + wsum[3]);
}

// ---------------- Kernel B (path1): p2 = column-sum of s0 over groups → loss_c ----------------
// grid = 128, block = 256; each block covers 32 columns
__global__ __launch_bounds__(256) void kB(const float* __restrict__ s0,
                                          const float* __restrict__ obs2,
                                          float* __restrict__ lossC) {
    __shared__ float lds[8][32];
    const int tx = threadIdx.x & 31;
    const int ty = threadIdx.x >> 5;
    const int c = blockIdx.x * 32 + tx;
    float acc = 0.f;
    for (int g = ty; g < 1024; g += 8)
        acc += s0[(size_t)g * 4096 + c];
    lds[ty][tx] = acc;
    __syncthreads();
    if (ty == 0) {
        float s = 0.f;
        #pragma unroll
        for (int k = 0; k < 8; ++k) s += lds[k][tx];
        float d = obs2[c] - s;
        atomicAdd(lossC, d * d);
    }
}

// ---------------- Kernel B2 (path2): reduce replicated p2 → loss_c ----------------
__global__ __launch_bounds__(256) void kB2(const float* __restrict__ p2r,
                                           const float* __restrict__ obs2,
                                           float* __restrict__ lossC,
                                           int R) {
    const int c = blockIdx.x * 256 + threadIdx.x;  // grid 16
    float s = 0.f;
    for (int r = 0; r < R; ++r) s += p2r[(size_t)r * 4096 + c];
    float d = obs2[c] - s;
    atomicAdd(lossC, d * d);
}

// ---------------- Kernel C: p1[row] = sum_k exp(theta1[row][k]) ----------------
// grid = 1024, block = 256 (one wave per row, 4 rows/block)
__global__ __launch_bounds__(256) void kC(const float4* __restrict__ theta1,
                                          float* __restrict__ p1) {
    const int lane = threadIdx.x & 63;
    const int row = blockIdx.x * 4 + (threadIdx.x >> 6);
    const float4* rp = theta1 + (size_t)row * 512;
    float acc = 0.f;
    #pragma unroll 2
    for (int i = lane; i < 512; i += 64) {
        float4 v = rp[i];
        acc += __expf(v.x) + __expf(v.y) + __expf(v.z) + __expf(v.w);
    }
    acc = wave_reduce(acc);
    if (lane == 0) p1[row] = acc;
}

// ---------------- Kernel D: m1 = mapping1 @ p1 → loss_b ----------------
// grid = 128, block = 256 (one wave per output row)
__global__ __launch_bounds__(256) void kD(const float4* __restrict__ mapping1,
                                          const float4* __restrict__ p1,
                                          const float* __restrict__ obs1,
                                          float* __restrict__ lossB) {
    const int lane = threadIdx.x & 63;
    const int row = blockIdx.x * 4 + (threadIdx.x >> 6);
    const float4* rp = mapping1 + (size_t)row * 1024;
    float acc = 0.f;
    #pragma unroll 2
    for (int i = lane; i < 1024; i += 64) {
        float4 m = rp[i];
        float4 p = p1[i];
        acc += m.x * p.x + m.y * p.y + m.z * p.z + m.w * p.w;
    }
    acc = wave_reduce(acc);
    if (lane == 0) {
        float d = obs1[row] - acc;
        atomicAdd(lossB, d * d);
    }
}

// ---------------- Kernel E: combine losses ----------------
__global__ void kE(const float* __restrict__ losses, float* __restrict__ out) {
    float la = losses[0] / (1024.f * 4096.f);
    float lb = losses[1] / 512.f;
    float lc = 0.5f * losses[2] / 4096.f;
    out[0] = (la + lb + lc) / 3.f;
}

extern "C" void kernel_launch(void* const* d_in, const int* in_sizes, int n_in,
                              void* d_out, int out_size, void* d_ws, size_t ws_size,
                              hipStream_t stream) {
    const float* theta0   = (const float*)d_in[0];   // [8192,4096]
    const float* theta1   = (const float*)d_in[1];   // [4096,2048]
    const float* obs0     = (const float*)d_in[2];   // [1024,4096]
    const float* obs1     = (const float*)d_in[3];   // [512]
    const float* obs2     = (const float*)d_in[4];   // [4096]
    const int*   idx0     = (const int*)d_in[5];     // [8192]
    const float* mapping1 = (const float*)d_in[6];   // [512,4096]
    float* out = (float*)d_out;

    char* ws = (char*)d_ws;
    float* losses = (float*)ws;                 // [0]=lossA sum, [1]=lossB sum, [2]=lossC sum
    float* p1     = (float*)(ws + 16);          // 4096 floats
    char*  big    = ws + 32768;                 // s0 (16 MB) or p2 replicas

    const size_t S0_BYTES = (size_t)1024 * 4096 * 4;
    const bool path1 = ws_size >= 32768 + S0_BYTES;

    hipMemsetAsync(losses, 0, 16, stream);

    // theta1 path (independent of theta0 path)
    kC<<<1024, 256, 0, stream>>>((const float4*)theta1, p1);
    kD<<<128, 256, 0, stream>>>((const float4*)mapping1, (const float4*)p1, obs1, &losses[1]);

    if (path1) {
        kA<<<1024, 256, 0, stream>>>((const float4*)theta0, (const float4*)obs0, idx0,
                                     (float4*)big, &losses[0]);
        kB<<<128, 256, 0, stream>>>((const float*)big, obs2, &losses[2]);
    } else {
        int R = (ws_size >= 32768 + (size_t)8 * 4096 * 4) ? 8 : 1;
        hipMemsetAsync(big, 0, (size_t)R * 4096 * 4, stream);
        kA2<<<1024, 256, 0, stream>>>((const float4*)theta0, (const float4*)obs0, idx0,
                                      (float*)big, &losses[0], R);
        kB2<<<16, 256, 0, stream>>>((const float*)big, obs2, &losses[2], R);
    }

    kE<<<1, 1, 0, stream>>>(losses, out);
}

// Round 2
// 287.408 us; speedup vs baseline: 1.0700x; 1.0700x over previous
//
#include <hip/hip_runtime.h>

__device__ __forceinline__ float4 exp4(float4 v) {
    float4 r;
    r.x = __expf(v.x); r.y = __expf(v.y); r.z = __expf(v.z); r.w = __expf(v.w);
    return r;
}

__device__ __forceinline__ void acc4(float4& a, float4 e) {
    a.x += e.x; a.y += e.y; a.z += e.z; a.w += e.w;
}

__device__ __forceinline__ float wave_reduce(float v) {
    #pragma unroll
    for (int off = 32; off > 0; off >>= 1) v += __shfl_down(v, off, 64);
    return v;
}

// ---------------- kIdx: build CSR (offs[1025], rowlist[8192]) for the 1024 groups ----------------
// 1 block, 1024 threads
__global__ __launch_bounds__(1024) void kIdx(const int* __restrict__ idx,
                                             int* __restrict__ offs,
                                             int* __restrict__ rowlist) {
    __shared__ int cnt[1024];
    __shared__ int pos[1024];
    const int t = threadIdx.x;
    cnt[t] = 0;
    __syncthreads();
    for (int i = t; i < 8192; i += 1024) atomicAdd(&cnt[idx[i]], 1);
    __syncthreads();
    const int v = cnt[t];
    pos[t] = v;
    __syncthreads();
    // Hillis-Steele inclusive scan
    for (int d = 1; d < 1024; d <<= 1) {
        int add = (t >= d) ? pos[t - d] : 0;
        __syncthreads();
        pos[t] += add;
        __syncthreads();
    }
    const int excl = pos[t] - v;
    offs[t] = excl;
    if (t == 0) offs[1024] = 8192;
    cnt[t] = excl;  // reuse as scatter cursor
    __syncthreads();
    for (int i = t; i < 8192; i += 1024) {
        int g = idx[i];
        int p = atomicAdd(&cnt[g], 1);
        rowlist[p] = i;
    }
}

// ---------------- kA: per-(group, col-chunk) segment sums of exp(theta0) + loss_a, store s0 ------
// grid = 4096 (1024 groups x 4 chunks of 1024 cols), block = 256
__global__ __launch_bounds__(256) void kA_csr(const float4* __restrict__ theta0,
                                              const float4* __restrict__ obs0,
                                              const int* __restrict__ offs,
                                              const int* __restrict__ rowlist,
                                              float4* __restrict__ s0,
                                              float* __restrict__ lossA) {
    const int g     = blockIdx.x & 1023;
    const int chunk = blockIdx.x >> 10;
    const int tid   = threadIdx.x;
    const int beg = offs[g];
    const int end = offs[g + 1];
    const float4* base = theta0 + (size_t)chunk * 256 + tid;  // row stride = 1024 float4

    __shared__ int rws[256];
    __shared__ float wsum[4];

    float4 a0 = {0,0,0,0}, a1 = {0,0,0,0}, a2 = {0,0,0,0}, a3 = {0,0,0,0};

    for (int t0 = beg; t0 < end; t0 += 256) {
        const int m = min(256, end - t0);
        __syncthreads();
        if (tid < m) rws[tid] = rowlist[t0 + tid];
        __syncthreads();
        int r = 0;
        for (; r + 4 <= m; r += 4) {
            const float4 v0 = base[(size_t)rws[r + 0] * 1024];
            const float4 v1 = base[(size_t)rws[r + 1] * 1024];
            const float4 v2 = base[(size_t)rws[r + 2] * 1024];
            const float4 v3 = base[(size_t)rws[r + 3] * 1024];
            acc4(a0, exp4(v0));
            acc4(a1, exp4(v1));
            acc4(a2, exp4(v2));
            acc4(a3, exp4(v3));
        }
        for (; r < m; ++r) {
            acc4(a0, exp4(base[(size_t)rws[r] * 1024]));
        }
    }

    float4 s;
    s.x = a0.x + a1.x + a2.x + a3.x;
    s.y = a0.y + a1.y + a2.y + a3.y;
    s.z = a0.z + a1.z + a2.z + a3.z;
    s.w = a0.w + a1.w + a2.w + a3.w;

    const size_t o = (size_t)g * 1024 + (size_t)chunk * 256 + tid;
    s0[o] = s;
    const float4 ob = obs0[o];
    const float dx = ob.x - s.x, dy = ob.y - s.y, dz = ob.z - s.z, dw = ob.w - s.w;
    float l = dx*dx + dy*dy + dz*dz + dw*dw;

    l = wave_reduce(l);
    if ((tid & 63) == 0) wsum[tid >> 6] = l;
    __syncthreads();
    if (tid == 0) atomicAdd(lossA, wsum[0] + wsum[1] + wsum[2] + wsum[3]);
}

// ---------------- kB: partial column sums of s0 -> atomicAdd into p2[4096] ----------------
// grid = 256 (64 col-groups x 4 row-chunks), block = 256
__global__ __launch_bounds__(256) void kB_part(const float* __restrict__ s0,
                                               float* __restrict__ p2) {
    const int lane = threadIdx.x & 63;
    const int ty   = threadIdx.x >> 6;   // 0..3
    const int cg   = blockIdx.x & 63;    // 64 column groups of 64 cols
    const int rc   = blockIdx.x >> 6;    // 4 row chunks of 256 groups
    const int col  = cg * 64 + lane;

    __shared__ float lds[4][64];

    const float* p = s0 + (size_t)(rc * 256 + ty) * 4096 + col;
    float acc = 0.f;
    #pragma unroll 4
    for (int k = 0; k < 64; ++k) acc += p[(size_t)k * 4 * 4096];

    lds[ty][lane] = acc;
    __syncthreads();
    if (ty == 0) {
        atomicAdd(&p2[col], lds[0][lane] + lds[1][lane] + lds[2][lane] + lds[3][lane]);
    }
}

// ---------------- kC: p1[row] = sum_k exp(theta1[row][k]) ----------------
// grid = 1024, block = 256 (one wave per row)
__global__ __launch_bounds__(256) void kC(const float4* __restrict__ theta1,
                                          float* __restrict__ p1) {
    const int lane = threadIdx.x & 63;
    const int row = blockIdx.x * 4 + (threadIdx.x >> 6);
    const float4* rp = theta1 + (size_t)row * 512;
    float acc = 0.f;
    #pragma unroll 2
    for (int i = lane; i < 512; i += 64) {
        float4 v = rp[i];
        acc += __expf(v.x) + __expf(v.y) + __expf(v.z) + __expf(v.w);
    }
    acc = wave_reduce(acc);
    if (lane == 0) p1[row] = acc;
}

// ---------------- kD: m1 = mapping1 @ p1 -> loss_b ----------------
// grid = 128, block = 256 (one wave per output row)
__global__ __launch_bounds__(256) void kD(const float4* __restrict__ mapping1,
                                          const float4* __restrict__ p1,
                                          const float* __restrict__ obs1,
                                          float* __restrict__ lossB) {
    const int lane = threadIdx.x & 63;
    const int row = blockIdx.x * 4 + (threadIdx.x >> 6);
    const float4* rp = mapping1 + (size_t)row * 1024;
    float acc = 0.f;
    #pragma unroll 2
    for (int i = lane; i < 1024; i += 64) {
        float4 m = rp[i];
        float4 p = p1[i];
        acc += m.x * p.x + m.y * p.y + m.z * p.z + m.w * p.w;
    }
    acc = wave_reduce(acc);
    if (lane == 0) {
        float d = obs1[row] - acc;
        atomicAdd(lossB, d * d);
    }
}

// ---------------- kE: loss_c from p2 + final combine ----------------
// 1 block, 1024 threads
__global__ __launch_bounds__(1024) void kE(const float4* __restrict__ p2v,
                                           const float4* __restrict__ obs2v,
                                           const float* __restrict__ losses,
                                           float* __restrict__ out) {
    __shared__ float wsum[16];
    const int tid = threadIdx.x;
    const float4 p = p2v[tid];
    const float4 o = obs2v[tid];
    const float dx = o.x - p.x, dy = o.y - p.y, dz = o.z - p.z, dw = o.w - p.w;
    float l = dx*dx + dy*dy + dz*dz + dw*dw;
    l = wave_reduce(l);
    if ((tid & 63) == 0) wsum[tid >> 6] = l;
    __syncthreads();
    if (tid == 0) {
        float sc = 0.f;
        #pragma unroll
        for (int i = 0; i < 16; ++i) sc += wsum[i];
        const float la = losses[0] / 4194304.f;   // mean over 1024*4096
        const float lb = losses[1] / 512.f;
        const float lc = 0.5f * sc / 4096.f;
        out[0] = (la + lb + lc) / 3.f;
    }
}

// ---------------- fallback (small ws): in-block scan + replicated atomics ----------------
#define ROWCAP 1024
__global__ __launch_bounds__(256) void kA2(const float4* __restrict__ theta0,
                                           const float4* __restrict__ obs0,
                                           const int* __restrict__ idx,
                                           float* __restrict__ p2,
                                           float* __restrict__ lossA) {
    __shared__ int rows[ROWCAP];
    __shared__ int cnt;
    __shared__ float wsum[4];
    const int g = blockIdx.x & 1023;
    const int chunk = blockIdx.x >> 10;
    const int tid = threadIdx.x;
    if (tid == 0) cnt = 0;
    __syncthreads();
    for (int i = tid; i < 8192; i += 256)
        if (idx[i] == g) { int p = atomicAdd(&cnt, 1); if (p < ROWCAP) rows[p] = i; }
    __syncthreads();
    const int n = min(cnt, ROWCAP);
    const float4* base = theta0 + (size_t)chunk * 256 + tid;
    float4 a0 = {0,0,0,0};
    for (int r = 0; r < n; ++r) acc4(a0, exp4(base[(size_t)rows[r] * 1024]));
    const size_t o = (size_t)g * 1024 + (size_t)chunk * 256 + tid;
    const int c = chunk * 1024 + tid * 4;
    atomicAdd(&p2[c + 0], a0.x);
    atomicAdd(&p2[c + 1], a0.y);
    atomicAdd(&p2[c + 2], a0.z);
    atomicAdd(&p2[c + 3], a0.w);
    const float4 ob = obs0[o];
    const float dx = ob.x - a0.x, dy = ob.y - a0.y, dz = ob.z - a0.z, dw = ob.w - a0.w;
    float l = dx*dx + dy*dy + dz*dz + dw*dw;
    l = wave_reduce(l);
    if ((tid & 63) == 0) wsum[tid >> 6] = l;
    __syncthreads();
    if (tid == 0) atomicAdd(lossA, wsum[0] + wsum[1] + wsum[2] + wsum[3]);
}

extern "C" void kernel_launch(void* const* d_in, const int* in_sizes, int n_in,
                              void* d_out, int out_size, void* d_ws, size_t ws_size,
                              hipStream_t stream) {
    const float* theta0   = (const float*)d_in[0];   // [8192,4096]
    const float* theta1   = (const float*)d_in[1];   // [4096,2048]
    const float* obs0     = (const float*)d_in[2];   // [1024,4096]
    const float* obs1     = (const float*)d_in[3];   // [512]
    const float* obs2     = (const float*)d_in[4];   // [4096]
    const int*   idx0     = (const int*)d_in[5];     // [8192]
    const float* mapping1 = (const float*)d_in[6];   // [512,4096]
    float* out = (float*)d_out;

    char* ws = (char*)d_ws;
    float* losses  = (float*)(ws + 0);        // 3 floats used
    float* p2      = (float*)(ws + 1024);     // 4096 floats (16 KB), ends 17408
    int*   offs    = (int*)(ws + 17408);      // 1025 ints, ends 21508
    int*   rowlist = (int*)(ws + 21760);      // 8192 ints, ends 54528
    float* p1      = (float*)(ws + 54784);    // 4096 floats, ends 71168
    float* s0      = (float*)(ws + 71680);    // 16 MB

    const size_t NEED = 71680 + (size_t)1024 * 4096 * 4;
    const bool path1 = ws_size >= NEED;

    // zero losses + p2 in one shot
    hipMemsetAsync(ws, 0, 17408, stream);

    if (path1) {
        kIdx<<<1, 1024, 0, stream>>>(idx0, offs, rowlist);
        kA_csr<<<4096, 256, 0, stream>>>((const float4*)theta0, (const float4*)obs0,
                                         offs, rowlist, (float4*)s0, &losses[0]);
        kB_part<<<256, 256, 0, stream>>>(s0, p2);
    } else {
        kA2<<<4096, 256, 0, stream>>>((const float4*)theta0, (const float4*)obs0,
                                      idx0, p2, &losses[0]);
    }

    kC<<<1024, 256, 0, stream>>>((const float4*)theta1, p1);
    kD<<<128, 256, 0, stream>>>((const float4*)mapping1, (const float4*)p1, obs1, &losses[1]);

    kE<<<1, 1024, 0, stream>>>((const float4*)p2, (const float4*)obs2, losses, out);
}

// Round 3
// 268.311 us; speedup vs baseline: 1.1462x; 1.0712x over previous
//
#include <hip/hip_runtime.h>

__device__ __forceinline__ float4 exp4(float4 v) {
    float4 r;
    r.x = __expf(v.x); r.y = __expf(v.y); r.z = __expf(v.z); r.w = __expf(v.w);
    return r;
}

__device__ __forceinline__ void acc4(float4& a, float4 e) {
    a.x += e.x; a.y += e.y; a.z += e.z; a.w += e.w;
}

__device__ __forceinline__ float wave_reduce(float v) {
    #pragma unroll
    for (int off = 32; off > 0; off >>= 1) v += __shfl_down(v, off, 64);
    return v;
}

// ================= K1: block 0 = CSR build; blocks 1..128 = theta1+mapping path ==============
// grid = 129, block = 1024
__global__ __launch_bounds__(1024) void K1(const int* __restrict__ idx,
                                           int* __restrict__ offs,
                                           int* __restrict__ rowlist,
                                           const float4* __restrict__ theta1,
                                           const float4* __restrict__ mapping1,
                                           float* __restrict__ m1,
                                           int do_csr) {
    if (blockIdx.x == 0) {
        if (!do_csr) return;
        __shared__ int cnt[1024];
        __shared__ int cur[1024];
        __shared__ int wsum[16];
        const int t = threadIdx.x, lane = t & 63, wave = t >> 6;
        cnt[t] = 0;
        __syncthreads();
        #pragma unroll
        for (int i = 0; i < 8; ++i) atomicAdd(&cnt[idx[t + i * 1024]], 1);
        __syncthreads();
        const int orig = cnt[t];
        int v = orig;
        #pragma unroll
        for (int off = 1; off < 64; off <<= 1) {
            int u = __shfl_up(v, off);
            if (lane >= off) v += u;
        }
        if (lane == 63) wsum[wave] = v;
        __syncthreads();
        if (t < 16) {
            int w = wsum[t];
            #pragma unroll
            for (int off = 1; off < 16; off <<= 1) {
                int u = __shfl_up(w, off);
                if (t >= off) w += u;
            }
            wsum[t] = w;
        }
        __syncthreads();
        const int excl = v + (wave ? wsum[wave - 1] : 0) - orig;
        offs[t] = excl;
        if (t == 0) offs[1024] = 8192;
        cur[t] = excl;
        __syncthreads();
        #pragma unroll
        for (int i = 0; i < 8; ++i) {
            const int j = t + i * 1024;
            const int g = idx[j];
            const int p = atomicAdd(&cur[g], 1);
            rowlist[p] = j;
        }
    } else {
        __shared__ float p1s[32];
        const int b = blockIdx.x - 1;             // 0..127: col-slice of 32
        const int t = threadIdx.x, lane = t & 63, wave = t >> 6;
        #pragma unroll
        for (int rr = 0; rr < 2; ++rr) {
            const int lr = wave * 2 + rr;
            const float4* rp = theta1 + (size_t)(b * 32 + lr) * 512;
            float a = 0.f;
            #pragma unroll
            for (int i = 0; i < 8; ++i) {
                float4 x = rp[lane + i * 64];
                a += __expf(x.x) + __expf(x.y) + __expf(x.z) + __expf(x.w);
            }
            a = wave_reduce(a);
            if (lane == 0) p1s[lr] = a;
        }
        __syncthreads();
        const int r = t >> 1, h = t & 1;          // 2 threads per output row
        const float4* mp = mapping1 + (size_t)r * 1024 + b * 8 + h * 4;
        float s = 0.f;
        #pragma unroll
        for (int j = 0; j < 4; ++j) {
            float4 m = mp[j];
            s += m.x * p1s[h * 16 + j * 4 + 0] + m.y * p1s[h * 16 + j * 4 + 1]
               + m.z * p1s[h * 16 + j * 4 + 2] + m.w * p1s[h * 16 + j * 4 + 3];
        }
        s += __shfl_down(s, 1);
        if (h == 0) atomicAdd(&m1[r], s);
    }
}

// ================= K2: per-(group, col-chunk) segment sums of exp(theta0) + loss_a ===========
// grid = 4096 (1024 groups x 4 chunks of 1024 cols), block = 256
__global__ __launch_bounds__(256) void K2(const float4* __restrict__ theta0,
                                          const float4* __restrict__ obs0,
                                          const int* __restrict__ offs,
                                          const int* __restrict__ rowlist,
                                          float4* __restrict__ s0,
                                          float* __restrict__ lossA) {
    const int g     = blockIdx.x & 1023;
    const int chunk = blockIdx.x >> 10;
    const int tid   = threadIdx.x;
    const int beg = offs[g];
    const int end = offs[g + 1];
    const float4* base = theta0 + (size_t)chunk * 256 + tid;  // row stride = 1024 float4

    __shared__ int rws[256];
    __shared__ float wsum[4];

    float4 a0 = {0,0,0,0}, a1 = {0,0,0,0}, a2 = {0,0,0,0}, a3 = {0,0,0,0};

    for (int t0 = beg; t0 < end; t0 += 256) {
        const int m = min(256, end - t0);
        __syncthreads();
        if (tid < m) rws[tid] = rowlist[t0 + tid];
        __syncthreads();
        int r = 0;
        for (; r + 4 <= m; r += 4) {
            const float4 v0 = base[(size_t)rws[r + 0] * 1024];
            const float4 v1 = base[(size_t)rws[r + 1] * 1024];
            const float4 v2 = base[(size_t)rws[r + 2] * 1024];
            const float4 v3 = base[(size_t)rws[r + 3] * 1024];
            acc4(a0, exp4(v0));
            acc4(a1, exp4(v1));
            acc4(a2, exp4(v2));
            acc4(a3, exp4(v3));
        }
        for (; r < m; ++r) acc4(a0, exp4(base[(size_t)rws[r] * 1024]));
    }

    float4 s;
    s.x = a0.x + a1.x + a2.x + a3.x;
    s.y = a0.y + a1.y + a2.y + a3.y;
    s.z = a0.z + a1.z + a2.z + a3.z;
    s.w = a0.w + a1.w + a2.w + a3.w;

    const size_t o = (size_t)g * 1024 + (size_t)chunk * 256 + tid;
    s0[o] = s;
    const float4 ob = obs0[o];
    const float dx = ob.x - s.x, dy = ob.y - s.y, dz = ob.z - s.z, dw = ob.w - s.w;
    float l = dx*dx + dy*dy + dz*dz + dw*dw;

    l = wave_reduce(l);
    if ((tid & 63) == 0) wsum[tid >> 6] = l;
    __syncthreads();
    if (tid == 0) atomicAdd(lossA, wsum[0] + wsum[1] + wsum[2] + wsum[3]);
}

// ================= K3: complete column sums of s0 + loss_c ==================================
// grid = 64 (64 cols each), block = 1024
__global__ __launch_bounds__(1024) void K3(const float* __restrict__ s0,
                                           const float* __restrict__ obs2,
                                           float* __restrict__ lossC) {
    __shared__ float part[16][64];
    const int lane = threadIdx.x & 63, wave = threadIdx.x >> 6;
    const int col = blockIdx.x * 64 + lane;
    const float* p = s0 + (size_t)wave * 4096 + col;
    float a = 0.f;
    #pragma unroll 4
    for (int g = 0; g < 64; ++g) a += p[(size_t)g * 16 * 4096];
    part[wave][lane] = a;
    __syncthreads();
    if (wave == 0) {
        float s = 0.f;
        #pragma unroll
        for (int k = 0; k < 16; ++k) s += part[k][lane];
        const float d = obs2[col] - s;
        const float l = wave_reduce(d * d);
        if (lane == 0) atomicAdd(lossC, l);
    }
}

// ================= K4: loss_b from m1 + final combine (+ fallback loss_c from p2) ===========
// grid = 1, block = 512
__global__ __launch_bounds__(512) void K4(const float* __restrict__ m1,
                                          const float* __restrict__ obs1,
                                          const float* __restrict__ losses,
                                          const float* __restrict__ p2,
                                          const float* __restrict__ obs2,
                                          int use_p2,
                                          float* __restrict__ out) {
    __shared__ float wb[8];
    __shared__ float wc[8];
    const int t = threadIdx.x, lane = t & 63, wave = t >> 6;
    const float d = obs1[t] - m1[t];
    const float lb = wave_reduce(d * d);
    float lc = 0.f;
    if (use_p2) {
        float acc = 0.f;
        #pragma unroll
        for (int i = 0; i < 8; ++i) {
            const int c = t + i * 512;
            const float dd = obs2[c] - p2[c];
            acc += dd * dd;
        }
        lc = wave_reduce(acc);
    }
    if (lane == 0) { wb[wave] = lb; wc[wave] = lc; }
    __syncthreads();
    if (t == 0) {
        float sb = 0.f, sc = 0.f;
        #pragma unroll
        for (int i = 0; i < 8; ++i) { sb += wb[i]; sc += wc[i]; }
        const float lossC = use_p2 ? sc : losses[2];
        const float la = losses[0] / 4194304.f;
        const float lbf = sb / 512.f;
        const float lcf = 0.5f * lossC / 4096.f;
        out[0] = (la + lbf + lcf) / 3.f;
    }
}

// ================= fallback (tiny ws): per-block idx scan + contended p2 atomics =============
#define ROWCAP 1024
__global__ __launch_bounds__(256) void kA2(const float4* __restrict__ theta0,
                                           const float4* __restrict__ obs0,
                                           const int* __restrict__ idx,
                                           float* __restrict__ p2,
                                           float* __restrict__ lossA) {
    __shared__ int rows[ROWCAP];
    __shared__ int cnt;
    __shared__ float wsum[4];
    const int g = blockIdx.x & 1023;
    const int chunk = blockIdx.x >> 10;
    const int tid = threadIdx.x;
    if (tid == 0) cnt = 0;
    __syncthreads();
    for (int i = tid; i < 8192; i += 256)
        if (idx[i] == g) { int p = atomicAdd(&cnt, 1); if (p < ROWCAP) rows[p] = i; }
    __syncthreads();
    const int n = min(cnt, ROWCAP);
    const float4* base = theta0 + (size_t)chunk * 256 + tid;
    float4 a0 = {0,0,0,0};
    for (int r = 0; r < n; ++r) acc4(a0, exp4(base[(size_t)rows[r] * 1024]));
    const size_t o = (size_t)g * 1024 + (size_t)chunk * 256 + tid;
    const int c = chunk * 1024 + tid * 4;
    atomicAdd(&p2[c + 0], a0.x);
    atomicAdd(&p2[c + 1], a0.y);
    atomicAdd(&p2[c + 2], a0.z);
    atomicAdd(&p2[c + 3], a0.w);
    const float4 ob = obs0[o];
    const float dx = ob.x - a0.x, dy = ob.y - a0.y, dz = ob.z - a0.z, dw = ob.w - a0.w;
    float l = dx*dx + dy*dy + dz*dz + dw*dw;
    l = wave_reduce(l);
    if ((tid & 63) == 0) wsum[tid >> 6] = l;
    __syncthreads();
    if (tid == 0) atomicAdd(lossA, wsum[0] + wsum[1] + wsum[2] + wsum[3]);
}

extern "C" void kernel_launch(void* const* d_in, const int* in_sizes, int n_in,
                              void* d_out, int out_size, void* d_ws, size_t ws_size,
                              hipStream_t stream) {
    const float* theta0   = (const float*)d_in[0];   // [8192,4096]
    const float* theta1   = (const float*)d_in[1];   // [4096,2048]
    const float* obs0     = (const float*)d_in[2];   // [1024,4096]
    const float* obs1     = (const float*)d_in[3];   // [512]
    const float* obs2     = (const float*)d_in[4];   // [4096]
    const int*   idx0     = (const int*)d_in[5];     // [8192]
    const float* mapping1 = (const float*)d_in[6];   // [512,4096]
    float* out = (float*)d_out;

    char* ws = (char*)d_ws;
    float* losses  = (float*)(ws + 0);        // [0]=lossA, [2]=lossC (raw sums)
    float* m1      = (float*)(ws + 256);      // 512 floats, ends 2304
    float* p2      = (float*)(ws + 4352);     // 4096 floats (fallback only), ends 20736
    int*   offs    = (int*)(ws + 24576);      // 1025 ints
    int*   rowlist = (int*)(ws + 28928);      // 8192 ints, ends 61696
    float* s0      = (float*)(ws + 65536);    // 16 MB

    const size_t NEED = 65536 + (size_t)1024 * 4096 * 4;
    const bool path1 = ws_size >= NEED;

    hipMemsetAsync(ws, 0, 20736, stream);  // losses + m1 + p2

    if (path1) {
        K1<<<129, 1024, 0, stream>>>(idx0, offs, rowlist, (const float4*)theta1,
                                     (const float4*)mapping1, m1, 1);
        K2<<<4096, 256, 0, stream>>>((const float4*)theta0, (const float4*)obs0,
                                     offs, rowlist, (float4*)s0, &losses[0]);
        K3<<<64, 1024, 0, stream>>>(s0, obs2, &losses[2]);
        K4<<<1, 512, 0, stream>>>(m1, obs1, losses, p2, obs2, 0, out);
    } else {
        K1<<<129, 1024, 0, stream>>>(idx0, nullptr, nullptr, (const float4*)theta1,
                                     (const float4*)mapping1, m1, 0);
        kA2<<<4096, 256, 0, stream>>>((const float4*)theta0, (const float4*)obs0,
                                      idx0, p2, &losses[0]);
        K4<<<1, 512, 0, stream>>>(m1, obs1, losses, p2, obs2, 1, out);
    }
}